// Round 10
// baseline (13828.712 us; speedup 1.0000x reference)
//
#include <hip/hip_runtime.h>
#include <hip/hip_bf16.h>
#include <stdint.h>

// ---------------------------------------------------------------------------
// Threefry-2x32-20
// ---------------------------------------------------------------------------
__device__ __forceinline__ uint32_t rotl32(uint32_t v, int s) {
    return (v << s) | (v >> (32 - s));
}

__device__ __forceinline__ void tf2x32(uint32_t k0, uint32_t k1,
                                       uint32_t x0, uint32_t x1,
                                       uint32_t& o0, uint32_t& o1) {
    uint32_t ks2 = k0 ^ k1 ^ 0x1BD11BDAu;
    x0 += k0; x1 += k1;
#define TFR(R0,R1,R2,R3) \
    x0 += x1; x1 = rotl32(x1, R0); x1 ^= x0; \
    x0 += x1; x1 = rotl32(x1, R1); x1 ^= x0; \
    x0 += x1; x1 = rotl32(x1, R2); x1 ^= x0; \
    x0 += x1; x1 = rotl32(x1, R3); x1 ^= x0;
    TFR(13,15,26,6)   x0 += k1;  x1 += ks2 + 1u;
    TFR(17,29,16,24)  x0 += ks2; x1 += k0  + 2u;
    TFR(13,15,26,6)   x0 += k0;  x1 += k1  + 3u;
    TFR(17,29,16,24)  x0 += k1;  x1 += ks2 + 4u;
    TFR(13,15,26,6)   x0 += ks2; x1 += k0  + 5u;
#undef TFR
    o0 = x0; o1 = x1;
}

// JAX partitionable random_bits (32-bit): bits = o0 ^ o1 of tf(key, hi=0, lo=j)
__device__ __forceinline__ uint32_t pbits32(uint32_t k0, uint32_t k1, uint32_t ctr) {
    uint32_t o0, o1;
    tf2x32(k0, k1, 0u, ctr, o0, o1);
    return o0 ^ o1;
}

// Literal JAX uniform + gumbel: u = max(tiny, (bits>>9)*2^-23); g = -log(-log(u))
__device__ __forceinline__ float gumbel_from_bits(uint32_t bits) {
    const float TINY = 1.17549435e-38f;
    float f = (float)(bits >> 9) * 1.1920928955078125e-7f;
    float u = fmaxf(TINY, f + TINY);
    return -logf(-logf(u));
}

#define NROW 64
#define NCOL 2048
#define NFLAT 131072
#define SPLIT 392

// ---------------------------------------------------------------------------
// keygen (partitionable foldlike split): keys[n] = (o0,o1) of tf((0,42),(0,n))
// ---------------------------------------------------------------------------
__global__ __launch_bounds__(256) void keygenF(uint32_t* __restrict__ kb) {
    int n = blockIdx.x * 256 + threadIdx.x;
    uint32_t o0, o1;
    tf2x32(0u, 42u, 0u, (uint32_t)n, o0, o1);
    kb[2 * n] = o0;
    kb[2 * n + 1] = o1;
}

// ---------------------------------------------------------------------------
// FFT real part -> x[64][2048]
// ---------------------------------------------------------------------------
__device__ __constant__ float c_ctab[8] = {
    1.0f, 0.70710678118654752f, 0.0f, -0.70710678118654752f,
   -1.0f, -0.70710678118654752f, 0.0f, 0.70710678118654752f
};

__global__ __launch_bounds__(256) void fft_x(const float* __restrict__ f,
                                             float* __restrict__ x) {
    int gid = blockIdx.x * 256 + threadIdx.x;
    int b = gid >> 10, i = gid & 1023;
    int c = i >> 6, h = (i >> 3) & 7, w = i & 7;
    const float* fb = f + ((b << 4) + c) * 64;
    float s = 0.0f;
#pragma unroll
    for (int hp = 0; hp < 8; ++hp) {
#pragma unroll
        for (int wp = 0; wp < 8; ++wp)
            s += fb[hp * 8 + wp] * c_ctab[(h * hp + w * wp) & 7];
    }
    x[b * NCOL + i] = s;
    x[b * NCOL + 1024 + i] = s;
}

// ---------------------------------------------------------------------------
// NAIVE literal linear + BN (+ReLU): one thread per (m,n), n wave-uniform.
// MODE 0: y = relu((dot + b - rm)/sqrt(rv+eps) * g + be)
// MODE 1: y =      (dot + b - rm)/sqrt(rv+eps)
// ---------------------------------------------------------------------------
template<int MODE>
__global__ __launch_bounds__(256)
void naive_fc(const float* __restrict__ A, const float* __restrict__ W,
              const float* __restrict__ bias,
              const float* __restrict__ rm, const float* __restrict__ rv,
              const float* __restrict__ gg, const float* __restrict__ be,
              float* __restrict__ out, int K, int N) {
    int tid = blockIdx.x * 256 + threadIdx.x;
    if (tid >= 64 * N) return;
    int n = tid >> 6;
    int m = tid & 63;
    const float* a = A + (size_t)m * K;
    const float* w = W + (size_t)n * K;
    float dot = 0.0f;
    for (int k = 0; k < K; ++k) dot = fmaf(a[k], w[k], dot);
    float v = dot + bias[n];
    v = (v - rm[n]) / sqrtf(rv[n] + 1e-5f);
    if (MODE == 0) {
        v = v * gg[n] + be[n];
        v = fmaxf(v, 0.0f);
    }
    out[(size_t)m * N + n] = v;
}

// ---------------------------------------------------------------------------
// Full in-register literal scan (1024 iterations), one block per row.
// Writes BOTH outputs in FLOAT32 (reference output dtype):
//   cols <392  -> out[r*392 + c]
//   cols >=392 -> out[25088 + r*1656 + (c-392)]
// ---------------------------------------------------------------------------
__global__ __launch_bounds__(1024)
void scan_full(const float* __restrict__ mraw, const uint32_t* __restrict__ kb,
               float* __restrict__ out) {
    const int r = blockIdx.x;
    const int tid = threadIdx.x;
    const int c0 = tid, c1 = tid + 1024;
    const int base = r * NCOL;
    float m0 = mraw[base + c0], m1 = mraw[base + c1];
    float z0 = 0.0f, z1 = 0.0f;
    __shared__ __align__(16) float redm[2][16];
    __shared__ __align__(16) float reds[2][16];
    const int lane = tid & 63, wid = tid >> 6;

    for (int t = 0; t < 1024; ++t) {
        uint32_t k0 = kb[2 * t], k1 = kb[2 * t + 1];
        float g0 = gumbel_from_bits(pbits32(k0, k1, (uint32_t)(base + c0)));
        float g1 = gumbel_from_bits(pbits32(k0, k1, (uint32_t)(base + c1)));

        float s0 = (m0 + g0) * 2.0f;
        float s1 = (m1 + g1) * 2.0f;

        float pm = fmaxf(s0, s1);
#pragma unroll
        for (int d = 1; d < 64; d <<= 1) pm = fmaxf(pm, __shfl_xor(pm, d, 64));
        if (lane == 0) redm[t & 1][wid] = pm;
        __syncthreads();
        {
            const float4* r4 = (const float4*)&redm[t & 1][0];
            float4 v0 = r4[0], v1 = r4[1], v2 = r4[2], v3 = r4[3];
            pm = fmaxf(fmaxf(fmaxf(v0.x, v0.y), fmaxf(v0.z, v0.w)),
                 fmaxf(fmaxf(fmaxf(v1.x, v1.y), fmaxf(v1.z, v1.w)),
                       fmaxf(fmaxf(fmaxf(v2.x, v2.y), fmaxf(v2.z, v2.w)),
                             fmaxf(fmaxf(v3.x, v3.y), fmaxf(v3.z, v3.w)))));
        }

        float p0 = expf(s0 - pm);
        float p1 = expf(s1 - pm);

        float ps = p0 + p1;
#pragma unroll
        for (int d = 1; d < 64; d <<= 1) ps += __shfl_xor(ps, d, 64);
        if (lane == 0) reds[t & 1][wid] = ps;
        __syncthreads();
        float S;
        {
            const float4* r4 = (const float4*)&reds[t & 1][0];
            float4 v0 = r4[0], v1 = r4[1], v2 = r4[2], v3 = r4[3];
            S = ((v0.x + v0.y) + (v0.z + v0.w)) + ((v1.x + v1.y) + (v1.z + v1.w))
              + ((v2.x + v2.y) + (v2.z + v2.w)) + ((v3.x + v3.y) + (v3.z + v3.w));
        }
        m0 = p0 / S; m1 = p1 / S;
        z0 = fmaxf(z0, m0); z1 = fmaxf(z1, m1);
    }

    // float32 output, both halves
    if (c0 < SPLIT) {
        out[r * SPLIT + c0] = z0;
    } else {
        out[64 * SPLIT + r * (NCOL - SPLIT) + (c0 - SPLIT)] = z0;
    }
    out[64 * SPLIT + r * (NCOL - SPLIT) + (c1 - SPLIT)] = z1;
}

// ---------------------------------------------------------------------------
// host
// ---------------------------------------------------------------------------
extern "C" void kernel_launch(void* const* d_in, const int* in_sizes, int n_in,
                              void* d_out, int out_size, void* d_ws, size_t ws_size,
                              hipStream_t stream) {
    const float* f   = (const float*)d_in[0];
    const float* W1  = (const float*)d_in[1];
    const float* b1  = (const float*)d_in[2];
    const float* g1  = (const float*)d_in[3];
    const float* be1 = (const float*)d_in[4];
    const float* rm1 = (const float*)d_in[5];
    const float* rv1 = (const float*)d_in[6];
    const float* W2  = (const float*)d_in[7];
    const float* b2  = (const float*)d_in[8];
    const float* g2  = (const float*)d_in[9];
    const float* be2 = (const float*)d_in[10];
    const float* rm2 = (const float*)d_in[11];
    const float* rv2 = (const float*)d_in[12];
    const float* W3  = (const float*)d_in[13];
    const float* b3  = (const float*)d_in[14];
    const float* rm3 = (const float*)d_in[15];
    const float* rv3 = (const float*)d_in[16];
    float* out = (float*)d_out;               // reference output dtype: float32

    float* ws = (float*)d_ws;
    size_t off = 0;
    auto alloc = [&](size_t n) { float* p = ws + off; off += n; return p; };

    uint32_t* keybuf = (uint32_t*)alloc(2048);
    float* x    = alloc(64 * 2048);
    float* h1   = alloc((size_t)64 * 8192);
    float* h2   = alloc((size_t)64 * 8192);
    float* mraw = alloc(NFLAT);

    keygenF<<<dim3(4), 256, 0, stream>>>(keybuf);
    fft_x<<<dim3(256), 256, 0, stream>>>(f, x);

    naive_fc<0><<<dim3(2048), 256, 0, stream>>>(x, W1, b1, rm1, rv1, g1, be1,
                                                h1, 2048, 8192);
    naive_fc<0><<<dim3(2048), 256, 0, stream>>>(h1, W2, b2, rm2, rv2, g2, be2,
                                                h2, 8192, 8192);
    naive_fc<1><<<dim3(512), 256, 0, stream>>>(h2, W3, b3, rm3, rv3, nullptr, nullptr,
                                               mraw, 8192, 2048);

    scan_full<<<dim3(64), 1024, 0, stream>>>(mraw, keybuf, out);
}

// Round 11
// 3021.226 us; speedup vs baseline: 4.5772x; 4.5772x over previous
//
#include <hip/hip_runtime.h>
#include <hip/hip_bf16.h>
#include <stdint.h>

// ---------------------------------------------------------------------------
// Threefry-2x32-20 + JAX partitionable bits (verified passing in round 10)
// ---------------------------------------------------------------------------
__device__ __forceinline__ uint32_t rotl32(uint32_t v, int s) {
    return (v << s) | (v >> (32 - s));
}

__device__ __forceinline__ void tf2x32(uint32_t k0, uint32_t k1,
                                       uint32_t x0, uint32_t x1,
                                       uint32_t& o0, uint32_t& o1) {
    uint32_t ks2 = k0 ^ k1 ^ 0x1BD11BDAu;
    x0 += k0; x1 += k1;
#define TFR(R0,R1,R2,R3) \
    x0 += x1; x1 = rotl32(x1, R0); x1 ^= x0; \
    x0 += x1; x1 = rotl32(x1, R1); x1 ^= x0; \
    x0 += x1; x1 = rotl32(x1, R2); x1 ^= x0; \
    x0 += x1; x1 = rotl32(x1, R3); x1 ^= x0;
    TFR(13,15,26,6)   x0 += k1;  x1 += ks2 + 1u;
    TFR(17,29,16,24)  x0 += ks2; x1 += k0  + 2u;
    TFR(13,15,26,6)   x0 += k0;  x1 += k1  + 3u;
    TFR(17,29,16,24)  x0 += k1;  x1 += ks2 + 4u;
    TFR(13,15,26,6)   x0 += ks2; x1 += k0  + 5u;
#undef TFR
    o0 = x0; o1 = x1;
}

__device__ __forceinline__ uint32_t pbits32(uint32_t k0, uint32_t k1, uint32_t ctr) {
    uint32_t o0, o1;
    tf2x32(k0, k1, 0u, ctr, o0, o1);
    return o0 ^ o1;
}

#define NROW 64
#define NCOL 2048
#define NFLAT 131072
#define SPLIT 392
#define C2 2.8853900817779268f    // 2/tau * log2(e) = 2*log2(e)

// gumbel (literal JAX): u = max(tiny, (bits>>9)*2^-23 + tiny); g = -log(-log(u))
__device__ __forceinline__ float gumbel_from_bits(uint32_t bits) {
    const float TINY = 1.17549435e-38f;
    float f = (float)(bits >> 9) * 1.1920928955078125e-7f;
    float u = fmaxf(TINY, f + TINY);
    return -logf(-logf(u));
}

// ---------------------------------------------------------------------------
// keygen (partitionable foldlike split): keys[n] = (o0,o1) of tf((0,42),(0,n))
// ---------------------------------------------------------------------------
__global__ __launch_bounds__(256) void keygenF(uint32_t* __restrict__ kb) {
    int n = blockIdx.x * 256 + threadIdx.x;
    uint32_t o0, o1;
    tf2x32(0u, 42u, 0u, (uint32_t)n, o0, o1);
    kb[2 * n] = o0;
    kb[2 * n + 1] = o1;
}

// ---------------------------------------------------------------------------
// FFT real part -> x[64][2048]
// ---------------------------------------------------------------------------
__device__ __constant__ float c_ctab[8] = {
    1.0f, 0.70710678118654752f, 0.0f, -0.70710678118654752f,
   -1.0f, -0.70710678118654752f, 0.0f, 0.70710678118654752f
};

__global__ __launch_bounds__(256) void fft_x(const float* __restrict__ f,
                                             float* __restrict__ x) {
    int gid = blockIdx.x * 256 + threadIdx.x;
    int b = gid >> 10, i = gid & 1023;
    int c = i >> 6, h = (i >> 3) & 7, w = i & 7;
    const float* fb = f + ((b << 4) + c) * 64;
    float s = 0.0f;
#pragma unroll
    for (int hp = 0; hp < 8; ++hp) {
#pragma unroll
        for (int wp = 0; wp < 8; ++wp)
            s += fb[hp * 8 + wp] * c_ctab[(h * hp + w * wp) & 7];
    }
    x[b * NCOL + i] = s;
    x[b * NCOL + 1024 + i] = s;
}

// ---------------------------------------------------------------------------
// prep: fold BN1/BN2 + bias into per-k affine: y = relu(dot*s + o)
// ---------------------------------------------------------------------------
__global__ __launch_bounds__(256) void prep(
    const float* __restrict__ b1, const float* __restrict__ g1,
    const float* __restrict__ be1, const float* __restrict__ rm1, const float* __restrict__ rv1,
    const float* __restrict__ b2, const float* __restrict__ g2,
    const float* __restrict__ be2, const float* __restrict__ rm2, const float* __restrict__ rv2,
    float* __restrict__ s1, float* __restrict__ o1,
    float* __restrict__ s2, float* __restrict__ o2) {
    int i = blockIdx.x * 256 + threadIdx.x;     // [0,8192)
    const float eps = 1e-5f;
    float inv = 1.0f / sqrtf(rv1[i] + eps);
    float s = g1[i] * inv;
    s1[i] = s; o1[i] = (b1[i] - rm1[i]) * s + be1[i];
    inv = 1.0f / sqrtf(rv2[i] + eps);
    s = g2[i] * inv;
    s2[i] = s; o2[i] = (b2[i] - rm2[i]) * s + be2[i];
}

// ---------------------------------------------------------------------------
// fp32 TN GEMM (full-K): C[64,N] = stage(A)[64,K] * B[N,K]^T
// stage = relu(a*s + o) if AFF. BM=64 BN=128 BK=32, 256 thr, 4x8/thread.
// (structure proven winner-pattern-identical to naive_fc in rounds 5-8)
// ---------------------------------------------------------------------------
template<bool AFF>
__global__ __launch_bounds__(256)
void gemm_tn(const float* __restrict__ A,
             const float* __restrict__ sA, const float* __restrict__ oA,
             const float* __restrict__ B, float* __restrict__ C,
             int K, int N) {
    __shared__ float As[32][68];
    __shared__ float Bs[32][132];
    const int t = threadIdx.x;
    const int n0 = blockIdx.x * 128;
    const int tm = t >> 4, tn = t & 15;

    float acc[4][8];
#pragma unroll
    for (int i = 0; i < 4; ++i)
#pragma unroll
        for (int j = 0; j < 8; ++j) acc[i][j] = 0.0f;

    for (int kt = 0; kt < K; kt += 32) {
#pragma unroll
        for (int h = 0; h < 2; ++h) {
            int idx = h * 1024 + t * 4;
            int am = idx >> 5, ak = idx & 31;
            size_t go = (size_t)am * K + kt + ak;
            float4 v = *(const float4*)(A + go);
            if (AFF) {
                float4 s = *(const float4*)(sA + kt + ak);
                float4 o = *(const float4*)(oA + kt + ak);
                v.x = fmaxf(v.x * s.x + o.x, 0.0f);
                v.y = fmaxf(v.y * s.y + o.y, 0.0f);
                v.z = fmaxf(v.z * s.z + o.z, 0.0f);
                v.w = fmaxf(v.w * s.w + o.w, 0.0f);
            }
            As[ak + 0][am] = v.x; As[ak + 1][am] = v.y;
            As[ak + 2][am] = v.z; As[ak + 3][am] = v.w;
        }
#pragma unroll
        for (int h = 0; h < 4; ++h) {
            int idx = h * 1024 + t * 4;
            int bn = idx >> 5, bk = idx & 31;
            float4 v = *(const float4*)(B + (size_t)(n0 + bn) * K + kt + bk);
            Bs[bk + 0][bn] = v.x; Bs[bk + 1][bn] = v.y;
            Bs[bk + 2][bn] = v.z; Bs[bk + 3][bn] = v.w;
        }
        __syncthreads();
#pragma unroll 8
        for (int kk = 0; kk < 32; ++kk) {
            float4 av = *(const float4*)&As[kk][tm << 2];
            float4 b0 = *(const float4*)&Bs[kk][tn << 3];
            float4 b1 = *(const float4*)&Bs[kk][(tn << 3) + 4];
            float a4[4] = {av.x, av.y, av.z, av.w};
            float b8[8] = {b0.x, b0.y, b0.z, b0.w, b1.x, b1.y, b1.z, b1.w};
#pragma unroll
            for (int i = 0; i < 4; ++i)
#pragma unroll
                for (int j = 0; j < 8; ++j)
                    acc[i][j] = fmaf(a4[i], b8[j], acc[i][j]);
        }
        __syncthreads();
    }
#pragma unroll
    for (int i = 0; i < 4; ++i) {
        size_t co = (size_t)((tm << 2) + i) * N + n0 + (tn << 3);
        float4 v0 = {acc[i][0], acc[i][1], acc[i][2], acc[i][3]};
        float4 v1 = {acc[i][4], acc[i][5], acc[i][6], acc[i][7]};
        *(float4*)(C + co) = v0;
        *(float4*)(C + co + 4) = v1;
    }
}

// ---------------------------------------------------------------------------
// L3 GEMM, k-split x4: part[p][64][2048] = stage(A)[:,p*2048:(p+1)*2048] * W3^T
// grid (16, 4). K=8192, Kc=2048, N=2048.
// ---------------------------------------------------------------------------
__global__ __launch_bounds__(256)
void gemm_l3(const float* __restrict__ A,
             const float* __restrict__ sA, const float* __restrict__ oA,
             const float* __restrict__ B, float* __restrict__ Cpart) {
    __shared__ float As[32][68];
    __shared__ float Bs[32][132];
    const int t = threadIdx.x;
    const int n0 = blockIdx.x * 128;
    const int k0 = blockIdx.y * 2048;
    const int tm = t >> 4, tn = t & 15;
    const int K = 8192, N = 2048;

    float acc[4][8];
#pragma unroll
    for (int i = 0; i < 4; ++i)
#pragma unroll
        for (int j = 0; j < 8; ++j) acc[i][j] = 0.0f;

    for (int kt = k0; kt < k0 + 2048; kt += 32) {
#pragma unroll
        for (int h = 0; h < 2; ++h) {
            int idx = h * 1024 + t * 4;
            int am = idx >> 5, ak = idx & 31;
            size_t go = (size_t)am * K + kt + ak;
            float4 v = *(const float4*)(A + go);
            float4 s = *(const float4*)(sA + kt + ak);
            float4 o = *(const float4*)(oA + kt + ak);
            v.x = fmaxf(v.x * s.x + o.x, 0.0f);
            v.y = fmaxf(v.y * s.y + o.y, 0.0f);
            v.z = fmaxf(v.z * s.z + o.z, 0.0f);
            v.w = fmaxf(v.w * s.w + o.w, 0.0f);
            As[ak + 0][am] = v.x; As[ak + 1][am] = v.y;
            As[ak + 2][am] = v.z; As[ak + 3][am] = v.w;
        }
#pragma unroll
        for (int h = 0; h < 4; ++h) {
            int idx = h * 1024 + t * 4;
            int bn = idx >> 5, bk = idx & 31;
            float4 v = *(const float4*)(B + (size_t)(n0 + bn) * K + kt + bk);
            Bs[bk + 0][bn] = v.x; Bs[bk + 1][bn] = v.y;
            Bs[bk + 2][bn] = v.z; Bs[bk + 3][bn] = v.w;
        }
        __syncthreads();
#pragma unroll 8
        for (int kk = 0; kk < 32; ++kk) {
            float4 av = *(const float4*)&As[kk][tm << 2];
            float4 b0 = *(const float4*)&Bs[kk][tn << 3];
            float4 b1 = *(const float4*)&Bs[kk][(tn << 3) + 4];
            float a4[4] = {av.x, av.y, av.z, av.w};
            float b8[8] = {b0.x, b0.y, b0.z, b0.w, b1.x, b1.y, b1.z, b1.w};
#pragma unroll
            for (int i = 0; i < 4; ++i)
#pragma unroll
                for (int j = 0; j < 8; ++j)
                    acc[i][j] = fmaf(a4[i], b8[j], acc[i][j]);
        }
        __syncthreads();
    }
#pragma unroll
    for (int i = 0; i < 4; ++i) {
        size_t co = (size_t)blockIdx.y * (64 * 2048)
                  + (size_t)((tm << 2) + i) * N + n0 + (tn << 3);
        float4 v0 = {acc[i][0], acc[i][1], acc[i][2], acc[i][3]};
        float4 v1 = {acc[i][4], acc[i][5], acc[i][6], acc[i][7]};
        *(float4*)(Cpart + co) = v0;
        *(float4*)(Cpart + co + 4) = v1;
    }
}

// ---------------------------------------------------------------------------
// combine: m = ((sum of 4 partials) + b3 - rm3) / sqrt(rv3+eps)
// ---------------------------------------------------------------------------
__global__ __launch_bounds__(256) void combine(const float* __restrict__ parts,
                                               const float* __restrict__ b3,
                                               const float* __restrict__ rm3,
                                               const float* __restrict__ rv3,
                                               float* __restrict__ mstate) {
    int gid = blockIdx.x * 256 + threadIdx.x;   // [0,131072)
    int c = gid & 2047;
    float v = parts[gid] + parts[gid + NFLAT] + parts[gid + 2 * NFLAT]
            + parts[gid + 3 * NFLAT];
    mstate[gid] = (v + b3[c] - rm3[c]) / sqrtf(rv3[c] + 1e-5f);
}

// ---------------------------------------------------------------------------
// precompute C2-scaled gumbels: gbuf[tt][j] = C2 * gumbel(bits(key[t0+tt], j))
// ---------------------------------------------------------------------------
__global__ __launch_bounds__(256) void precomp_g(const uint32_t* __restrict__ kb,
                                                 float* __restrict__ gbuf, int t0) {
    int j = blockIdx.x * 256 + threadIdx.x;     // [0,131072)
    int tt = blockIdx.y;
    int tg = t0 + tt;
    uint32_t k0 = kb[2 * tg], k1 = kb[2 * tg + 1];
    gbuf[(size_t)tt * NFLAT + j] = gumbel_from_bits(pbits32(k0, k1, (uint32_t)j)) * C2;
}

// ---------------------------------------------------------------------------
// scan chunk (gumbels preloaded): p = exp2(m*C2 + g*C2); m' = p/S; z=max(z,m')
// No max-subtraction (softmax shift-invariant; args bounded: s <= ~64 ->
// exp2 <= 2^64, row sum <= 2^75 << fp32 max). One barrier/iter (dbuf LDS).
// ---------------------------------------------------------------------------
__global__ __launch_bounds__(1024)
void scan_chunk(float* __restrict__ mstate, float* __restrict__ zstate,
                const float* __restrict__ gbuf,
                int t0, int Tc, int last, float* __restrict__ out) {
    const int r = blockIdx.x;
    const int tid = threadIdx.x;
    const int c0 = tid, c1 = tid + 1024;
    const int base = r * NCOL;
    float m0 = mstate[base + c0], m1 = mstate[base + c1];
    float z0, z1;
    if (t0 == 0) { z0 = 0.0f; z1 = 0.0f; }
    else         { z0 = zstate[base + c0]; z1 = zstate[base + c1]; }
    __shared__ __align__(16) float red[2][16];
    const int lane = tid & 63, wid = tid >> 6;

    for (int tt = 0; tt < Tc; ++tt) {
        size_t ao = (size_t)tt * NFLAT + base;
        float g0 = gbuf[ao + c0];
        float g1 = gbuf[ao + c1];
        float p0 = exp2f(fmaf(m0, C2, g0));
        float p1 = exp2f(fmaf(m1, C2, g1));
        float ps = p0 + p1;
#pragma unroll
        for (int d = 1; d < 64; d <<= 1) ps += __shfl_xor(ps, d, 64);
        if (lane == 0) red[tt & 1][wid] = ps;
        __syncthreads();
        float S;
        {
            const float4* r4 = (const float4*)&red[tt & 1][0];
            float4 v0 = r4[0], v1 = r4[1], v2 = r4[2], v3 = r4[3];
            S = ((v0.x + v0.y) + (v0.z + v0.w)) + ((v1.x + v1.y) + (v1.z + v1.w))
              + ((v2.x + v2.y) + (v2.z + v2.w)) + ((v3.x + v3.y) + (v3.z + v3.w));
        }
        m0 = p0 / S; m1 = p1 / S;
        z0 = fmaxf(z0, m0); z1 = fmaxf(z1, m1);
    }
    mstate[base + c0] = m0; mstate[base + c1] = m1;
    zstate[base + c0] = z0; zstate[base + c1] = z1;
    if (last) {
        if (c0 < SPLIT) out[r * SPLIT + c0] = z0;
        else out[64 * SPLIT + r * (NCOL - SPLIT) + (c0 - SPLIT)] = z0;
        out[64 * SPLIT + r * (NCOL - SPLIT) + (c1 - SPLIT)] = z1;
    }
}

// ---------------------------------------------------------------------------
// inline-hash fallback (ws too small for gbuf): full 1024 iterations
// ---------------------------------------------------------------------------
__global__ __launch_bounds__(1024)
void scan_inline(const float* __restrict__ mstate, const uint32_t* __restrict__ kb,
                 float* __restrict__ out) {
    const int r = blockIdx.x;
    const int tid = threadIdx.x;
    const int c0 = tid, c1 = tid + 1024;
    const int base = r * NCOL;
    float m0 = mstate[base + c0], m1 = mstate[base + c1];
    float z0 = 0.0f, z1 = 0.0f;
    __shared__ __align__(16) float red[2][16];
    const int lane = tid & 63, wid = tid >> 6;

    for (int t = 0; t < 1024; ++t) {
        uint32_t k0 = kb[2 * t], k1 = kb[2 * t + 1];
        float g0 = gumbel_from_bits(pbits32(k0, k1, (uint32_t)(base + c0)));
        float g1 = gumbel_from_bits(pbits32(k0, k1, (uint32_t)(base + c1)));
        float p0 = exp2f((m0 + g0) * C2);
        float p1 = exp2f((m1 + g1) * C2);
        float ps = p0 + p1;
#pragma unroll
        for (int d = 1; d < 64; d <<= 1) ps += __shfl_xor(ps, d, 64);
        if (lane == 0) red[t & 1][wid] = ps;
        __syncthreads();
        float S;
        {
            const float4* r4 = (const float4*)&red[t & 1][0];
            float4 v0 = r4[0], v1 = r4[1], v2 = r4[2], v3 = r4[3];
            S = ((v0.x + v0.y) + (v0.z + v0.w)) + ((v1.x + v1.y) + (v1.z + v1.w))
              + ((v2.x + v2.y) + (v2.z + v2.w)) + ((v3.x + v3.y) + (v3.z + v3.w));
        }
        m0 = p0 / S; m1 = p1 / S;
        z0 = fmaxf(z0, m0); z1 = fmaxf(z1, m1);
    }
    if (c0 < SPLIT) out[r * SPLIT + c0] = z0;
    else out[64 * SPLIT + r * (NCOL - SPLIT) + (c0 - SPLIT)] = z0;
    out[64 * SPLIT + r * (NCOL - SPLIT) + (c1 - SPLIT)] = z1;
}

// ---------------------------------------------------------------------------
// host
// ---------------------------------------------------------------------------
extern "C" void kernel_launch(void* const* d_in, const int* in_sizes, int n_in,
                              void* d_out, int out_size, void* d_ws, size_t ws_size,
                              hipStream_t stream) {
    const float* f   = (const float*)d_in[0];
    const float* W1  = (const float*)d_in[1];
    const float* b1  = (const float*)d_in[2];
    const float* g1  = (const float*)d_in[3];
    const float* be1 = (const float*)d_in[4];
    const float* rm1 = (const float*)d_in[5];
    const float* rv1 = (const float*)d_in[6];
    const float* W2  = (const float*)d_in[7];
    const float* b2  = (const float*)d_in[8];
    const float* g2  = (const float*)d_in[9];
    const float* be2 = (const float*)d_in[10];
    const float* rm2 = (const float*)d_in[11];
    const float* rv2 = (const float*)d_in[12];
    const float* W3  = (const float*)d_in[13];
    const float* b3  = (const float*)d_in[14];
    const float* rm3 = (const float*)d_in[15];
    const float* rv3 = (const float*)d_in[16];
    float* out = (float*)d_out;               // reference output dtype: float32

    float* ws = (float*)d_ws;
    size_t off = 0;
    auto alloc = [&](size_t n) { float* p = ws + off; off += n; return p; };

    uint32_t* keybuf = (uint32_t*)alloc(2048);
    float* s1 = alloc(8192); float* o1 = alloc(8192);
    float* s2 = alloc(8192); float* o2 = alloc(8192);
    float* x      = alloc(64 * 2048);
    float* h1     = alloc((size_t)64 * 8192);   // L1 out; later L3 partials (4x64x2048)
    float* h2     = alloc((size_t)64 * 8192);
    float* mstate = alloc(NFLAT);
    float* zstate = alloc(NFLAT);
    size_t fixed = off;                         // ~5.7 MB
    float* gbuf = ws + fixed;

    int Tc = 0;
    const int cands[8] = {128, 64, 32, 16, 8, 4, 2, 1};
    for (int ci = 0; ci < 8; ++ci) {
        size_t need = (fixed + (size_t)cands[ci] * NFLAT) * 4;
        if (need <= ws_size) { Tc = cands[ci]; break; }
    }

    keygenF<<<dim3(4), 256, 0, stream>>>(keybuf);
    prep<<<dim3(32), 256, 0, stream>>>(b1, g1, be1, rm1, rv1,
                                       b2, g2, be2, rm2, rv2,
                                       s1, o1, s2, o2);
    fft_x<<<dim3(256), 256, 0, stream>>>(f, x);

    // L1: h1 = x @ W1^T (raw dot; BN1+bias folded into L2 staging)
    gemm_tn<false><<<dim3(64), 256, 0, stream>>>(x, nullptr, nullptr, W1, h1, 2048, 8192);
    // L2: h2 = relu(bn1(h1)) @ W2^T (raw dot; BN2 folded into L3 staging)
    gemm_tn<true><<<dim3(64), 256, 0, stream>>>(h1, s1, o1, W2, h2, 8192, 8192);
    // L3 k-split x4: partials into h1 (L1 output fully consumed by L2)
    gemm_l3<<<dim3(16, 4), 256, 0, stream>>>(h2, s2, o2, W3, h1);
    // combine partials + literal BN3 -> mstate
    combine<<<dim3(512), 256, 0, stream>>>(h1, b3, rm3, rv3, mstate);

    if (Tc > 0) {
        int NC = 1024 / Tc;
        for (int ch = 0; ch < NC; ++ch) {
            precomp_g<<<dim3(512, Tc), 256, 0, stream>>>(keybuf, gbuf, ch * Tc);
            scan_chunk<<<dim3(64), 1024, 0, stream>>>(
                mstate, zstate, gbuf, ch * Tc, Tc, (ch == NC - 1) ? 1 : 0, out);
        }
    } else {
        scan_inline<<<dim3(64), 1024, 0, stream>>>(mstate, keybuf, out);
    }
}

// Round 12
// 1629.203 us; speedup vs baseline: 8.4880x; 1.8544x over previous
//
#include <hip/hip_runtime.h>
#include <hip/hip_bf16.h>
#include <stdint.h>

// ---------------------------------------------------------------------------
// Threefry-2x32-20 + JAX partitionable bits (verified passing, rounds 10/11)
// ---------------------------------------------------------------------------
__device__ __forceinline__ uint32_t rotl32(uint32_t v, int s) {
    return (v << s) | (v >> (32 - s));
}

__device__ __forceinline__ void tf2x32(uint32_t k0, uint32_t k1,
                                       uint32_t x0, uint32_t x1,
                                       uint32_t& o0, uint32_t& o1) {
    uint32_t ks2 = k0 ^ k1 ^ 0x1BD11BDAu;
    x0 += k0; x1 += k1;
#define TFR(R0,R1,R2,R3) \
    x0 += x1; x1 = rotl32(x1, R0); x1 ^= x0; \
    x0 += x1; x1 = rotl32(x1, R1); x1 ^= x0; \
    x0 += x1; x1 = rotl32(x1, R2); x1 ^= x0; \
    x0 += x1; x1 = rotl32(x1, R3); x1 ^= x0;
    TFR(13,15,26,6)   x0 += k1;  x1 += ks2 + 1u;
    TFR(17,29,16,24)  x0 += ks2; x1 += k0  + 2u;
    TFR(13,15,26,6)   x0 += k0;  x1 += k1  + 3u;
    TFR(17,29,16,24)  x0 += k1;  x1 += ks2 + 4u;
    TFR(13,15,26,6)   x0 += ks2; x1 += k0  + 5u;
#undef TFR
    o0 = x0; o1 = x1;
}

__device__ __forceinline__ uint32_t pbits32(uint32_t k0, uint32_t k1, uint32_t ctr) {
    uint32_t o0, o1;
    tf2x32(k0, k1, 0u, ctr, o0, o1);
    return o0 ^ o1;
}

#define NROW 64
#define NCOL 2048
#define NFLAT 131072
#define SPLIT 392
#define C2 2.8853900817779268f    // 2/tau * log2(e)

__device__ __forceinline__ float gumbel_from_bits(uint32_t bits) {
    const float TINY = 1.17549435e-38f;
    float f = (float)(bits >> 9) * 1.1920928955078125e-7f;
    float u = fmaxf(TINY, f + TINY);
    return -logf(-logf(u));
}

// ---------------------------------------------------------------------------
// keygen (partitionable foldlike split)
// ---------------------------------------------------------------------------
__global__ __launch_bounds__(256) void keygenF(uint32_t* __restrict__ kb) {
    int n = blockIdx.x * 256 + threadIdx.x;
    uint32_t o0, o1;
    tf2x32(0u, 42u, 0u, (uint32_t)n, o0, o1);
    kb[2 * n] = o0;
    kb[2 * n + 1] = o1;
}

// ---------------------------------------------------------------------------
// FFT real part -> x[64][2048]
// ---------------------------------------------------------------------------
__device__ __constant__ float c_ctab[8] = {
    1.0f, 0.70710678118654752f, 0.0f, -0.70710678118654752f,
   -1.0f, -0.70710678118654752f, 0.0f, 0.70710678118654752f
};

__global__ __launch_bounds__(256) void fft_x(const float* __restrict__ f,
                                             float* __restrict__ x) {
    int gid = blockIdx.x * 256 + threadIdx.x;
    int b = gid >> 10, i = gid & 1023;
    int c = i >> 6, h = (i >> 3) & 7, w = i & 7;
    const float* fb = f + ((b << 4) + c) * 64;
    float s = 0.0f;
#pragma unroll
    for (int hp = 0; hp < 8; ++hp) {
#pragma unroll
        for (int wp = 0; wp < 8; ++wp)
            s += fb[hp * 8 + wp] * c_ctab[(h * hp + w * wp) & 7];
    }
    x[b * NCOL + i] = s;
    x[b * NCOL + 1024 + i] = s;
}

// ---------------------------------------------------------------------------
// prep: fold BN1/BN2 + bias into per-k affine: y = relu(dot*s + o)
// ---------------------------------------------------------------------------
__global__ __launch_bounds__(256) void prep(
    const float* __restrict__ b1, const float* __restrict__ g1,
    const float* __restrict__ be1, const float* __restrict__ rm1, const float* __restrict__ rv1,
    const float* __restrict__ b2, const float* __restrict__ g2,
    const float* __restrict__ be2, const float* __restrict__ rm2, const float* __restrict__ rv2,
    float* __restrict__ s1, float* __restrict__ o1,
    float* __restrict__ s2, float* __restrict__ o2) {
    int i = blockIdx.x * 256 + threadIdx.x;     // [0,8192)
    const float eps = 1e-5f;
    float inv = 1.0f / sqrtf(rv1[i] + eps);
    float s = g1[i] * inv;
    s1[i] = s; o1[i] = (b1[i] - rm1[i]) * s + be1[i];
    inv = 1.0f / sqrtf(rv2[i] + eps);
    s = g2[i] * inv;
    s2[i] = s; o2[i] = (b2[i] - rm2[i]) * s + be2[i];
}

// ---------------------------------------------------------------------------
// fp32 TN GEMM, k-split: Cpart[ksp][64][N] = stage(A)[:,ksp*Kc:(ksp+1)*Kc] * B^T
// stage = relu(a*s + o) if AFF. BM=64 BN=128 BK=32, 256 thr, 4x8/thread.
// grid (N/128, KS). Structure identical to validated r11 kernels.
// ---------------------------------------------------------------------------
template<bool AFF>
__global__ __launch_bounds__(256)
void gemm_ks(const float* __restrict__ A,
             const float* __restrict__ sA, const float* __restrict__ oA,
             const float* __restrict__ B, float* __restrict__ Cpart,
             int K, int Kc, int N) {
    __shared__ float As[32][68];
    __shared__ float Bs[32][132];
    const int t = threadIdx.x;
    const int n0 = blockIdx.x * 128;
    const int k0 = blockIdx.y * Kc;
    const int tm = t >> 4, tn = t & 15;

    float acc[4][8];
#pragma unroll
    for (int i = 0; i < 4; ++i)
#pragma unroll
        for (int j = 0; j < 8; ++j) acc[i][j] = 0.0f;

    for (int kt = k0; kt < k0 + Kc; kt += 32) {
#pragma unroll
        for (int h = 0; h < 2; ++h) {
            int idx = h * 1024 + t * 4;
            int am = idx >> 5, ak = idx & 31;
            size_t go = (size_t)am * K + kt + ak;
            float4 v = *(const float4*)(A + go);
            if (AFF) {
                float4 s = *(const float4*)(sA + kt + ak);
                float4 o = *(const float4*)(oA + kt + ak);
                v.x = fmaxf(v.x * s.x + o.x, 0.0f);
                v.y = fmaxf(v.y * s.y + o.y, 0.0f);
                v.z = fmaxf(v.z * s.z + o.z, 0.0f);
                v.w = fmaxf(v.w * s.w + o.w, 0.0f);
            }
            As[ak + 0][am] = v.x; As[ak + 1][am] = v.y;
            As[ak + 2][am] = v.z; As[ak + 3][am] = v.w;
        }
#pragma unroll
        for (int h = 0; h < 4; ++h) {
            int idx = h * 1024 + t * 4;
            int bn = idx >> 5, bk = idx & 31;
            float4 v = *(const float4*)(B + (size_t)(n0 + bn) * K + kt + bk);
            Bs[bk + 0][bn] = v.x; Bs[bk + 1][bn] = v.y;
            Bs[bk + 2][bn] = v.z; Bs[bk + 3][bn] = v.w;
        }
        __syncthreads();
#pragma unroll 8
        for (int kk = 0; kk < 32; ++kk) {
            float4 av = *(const float4*)&As[kk][tm << 2];
            float4 b0 = *(const float4*)&Bs[kk][tn << 3];
            float4 b1 = *(const float4*)&Bs[kk][(tn << 3) + 4];
            float a4[4] = {av.x, av.y, av.z, av.w};
            float b8[8] = {b0.x, b0.y, b0.z, b0.w, b1.x, b1.y, b1.z, b1.w};
#pragma unroll
            for (int i = 0; i < 4; ++i)
#pragma unroll
                for (int j = 0; j < 8; ++j)
                    acc[i][j] = fmaf(a4[i], b8[j], acc[i][j]);
        }
        __syncthreads();
    }
#pragma unroll
    for (int i = 0; i < 4; ++i) {
        size_t co = (size_t)blockIdx.y * ((size_t)64 * N)
                  + (size_t)((tm << 2) + i) * N + n0 + (tn << 3);
        float4 v0 = {acc[i][0], acc[i][1], acc[i][2], acc[i][3]};
        float4 v1 = {acc[i][4], acc[i][5], acc[i][6], acc[i][7]};
        *(float4*)(Cpart + co) = v0;
        *(float4*)(Cpart + co + 4) = v1;
    }
}

// ---------------------------------------------------------------------------
// combineP: dst = sum of P partials (each `total` elements)
// ---------------------------------------------------------------------------
__global__ __launch_bounds__(256) void combineP(const float* __restrict__ parts,
                                                float* __restrict__ dst,
                                                int P, int total) {
    int gid = blockIdx.x * 256 + threadIdx.x;
    if (gid >= total) return;
    float s = 0.0f;
    for (int p = 0; p < P; ++p) s += parts[(size_t)p * total + gid];
    dst[gid] = s;
}

// ---------------------------------------------------------------------------
// combine3: mstate = ((sum of P partials) + b3 - rm3) / sqrt(rv3+eps)
// ---------------------------------------------------------------------------
__global__ __launch_bounds__(256) void combine3(const float* __restrict__ parts,
                                                const float* __restrict__ b3,
                                                const float* __restrict__ rm3,
                                                const float* __restrict__ rv3,
                                                float* __restrict__ mstate, int P) {
    int gid = blockIdx.x * 256 + threadIdx.x;   // [0,131072)
    int c = gid & 2047;
    float v = 0.0f;
    for (int p = 0; p < P; ++p) v += parts[(size_t)p * NFLAT + gid];
    mstate[gid] = (v + b3[c] - rm3[c]) / sqrtf(rv3[c] + 1e-5f);
}

// ---------------------------------------------------------------------------
// precompute C2-scaled gumbels (identical to r11)
// ---------------------------------------------------------------------------
__global__ __launch_bounds__(256) void precomp_g(const uint32_t* __restrict__ kb,
                                                 float* __restrict__ gbuf, int t0) {
    int j = blockIdx.x * 256 + threadIdx.x;     // [0,131072)
    int tt = blockIdx.y;
    int tg = t0 + tt;
    uint32_t k0 = kb[2 * tg], k1 = kb[2 * tg + 1];
    gbuf[(size_t)tt * NFLAT + j] = gumbel_from_bits(pbits32(k0, k1, (uint32_t)j)) * C2;
}

// ---------------------------------------------------------------------------
// scan chunk (identical to r11, proven)
// ---------------------------------------------------------------------------
__global__ __launch_bounds__(1024)
void scan_chunk(float* __restrict__ mstate, float* __restrict__ zstate,
                const float* __restrict__ gbuf,
                int t0, int Tc, int last, float* __restrict__ out) {
    const int r = blockIdx.x;
    const int tid = threadIdx.x;
    const int c0 = tid, c1 = tid + 1024;
    const int base = r * NCOL;
    float m0 = mstate[base + c0], m1 = mstate[base + c1];
    float z0, z1;
    if (t0 == 0) { z0 = 0.0f; z1 = 0.0f; }
    else         { z0 = zstate[base + c0]; z1 = zstate[base + c1]; }
    __shared__ __align__(16) float red[2][16];
    const int lane = tid & 63, wid = tid >> 6;

    for (int tt = 0; tt < Tc; ++tt) {
        size_t ao = (size_t)tt * NFLAT + base;
        float g0 = gbuf[ao + c0];
        float g1 = gbuf[ao + c1];
        float p0 = exp2f(fmaf(m0, C2, g0));
        float p1 = exp2f(fmaf(m1, C2, g1));
        float ps = p0 + p1;
#pragma unroll
        for (int d = 1; d < 64; d <<= 1) ps += __shfl_xor(ps, d, 64);
        if (lane == 0) red[tt & 1][wid] = ps;
        __syncthreads();
        float S;
        {
            const float4* r4 = (const float4*)&red[tt & 1][0];
            float4 v0 = r4[0], v1 = r4[1], v2 = r4[2], v3 = r4[3];
            S = ((v0.x + v0.y) + (v0.z + v0.w)) + ((v1.x + v1.y) + (v1.z + v1.w))
              + ((v2.x + v2.y) + (v2.z + v2.w)) + ((v3.x + v3.y) + (v3.z + v3.w));
        }
        m0 = p0 / S; m1 = p1 / S;
        z0 = fmaxf(z0, m0); z1 = fmaxf(z1, m1);
    }
    mstate[base + c0] = m0; mstate[base + c1] = m1;
    zstate[base + c0] = z0; zstate[base + c1] = z1;
    if (last) {
        if (c0 < SPLIT) out[r * SPLIT + c0] = z0;
        else out[64 * SPLIT + r * (NCOL - SPLIT) + (c0 - SPLIT)] = z0;
        out[64 * SPLIT + r * (NCOL - SPLIT) + (c1 - SPLIT)] = z1;
    }
}

// ---------------------------------------------------------------------------
// inline-hash fallback (ws too small for gbuf)
// ---------------------------------------------------------------------------
__global__ __launch_bounds__(1024)
void scan_inline(const float* __restrict__ mstate, const uint32_t* __restrict__ kb,
                 float* __restrict__ out) {
    const int r = blockIdx.x;
    const int tid = threadIdx.x;
    const int c0 = tid, c1 = tid + 1024;
    const int base = r * NCOL;
    float m0 = mstate[base + c0], m1 = mstate[base + c1];
    float z0 = 0.0f, z1 = 0.0f;
    __shared__ __align__(16) float red[2][16];
    const int lane = tid & 63, wid = tid >> 6;

    for (int t = 0; t < 1024; ++t) {
        uint32_t k0 = kb[2 * t], k1 = kb[2 * t + 1];
        float g0 = gumbel_from_bits(pbits32(k0, k1, (uint32_t)(base + c0)));
        float g1 = gumbel_from_bits(pbits32(k0, k1, (uint32_t)(base + c1)));
        float p0 = exp2f((m0 + g0) * C2);
        float p1 = exp2f((m1 + g1) * C2);
        float ps = p0 + p1;
#pragma unroll
        for (int d = 1; d < 64; d <<= 1) ps += __shfl_xor(ps, d, 64);
        if (lane == 0) red[t & 1][wid] = ps;
        __syncthreads();
        float S;
        {
            const float4* r4 = (const float4*)&red[t & 1][0];
            float4 v0 = r4[0], v1 = r4[1], v2 = r4[2], v3 = r4[3];
            S = ((v0.x + v0.y) + (v0.z + v0.w)) + ((v1.x + v1.y) + (v1.z + v1.w))
              + ((v2.x + v2.y) + (v2.z + v2.w)) + ((v3.x + v3.y) + (v3.z + v3.w));
        }
        m0 = p0 / S; m1 = p1 / S;
        z0 = fmaxf(z0, m0); z1 = fmaxf(z1, m1);
    }
    if (c0 < SPLIT) out[r * SPLIT + c0] = z0;
    else out[64 * SPLIT + r * (NCOL - SPLIT) + (c0 - SPLIT)] = z0;
    out[64 * SPLIT + r * (NCOL - SPLIT) + (c1 - SPLIT)] = z1;
}

// ---------------------------------------------------------------------------
// host
// ---------------------------------------------------------------------------
extern "C" void kernel_launch(void* const* d_in, const int* in_sizes, int n_in,
                              void* d_out, int out_size, void* d_ws, size_t ws_size,
                              hipStream_t stream) {
    const float* f   = (const float*)d_in[0];
    const float* W1  = (const float*)d_in[1];
    const float* b1  = (const float*)d_in[2];
    const float* g1  = (const float*)d_in[3];
    const float* be1 = (const float*)d_in[4];
    const float* rm1 = (const float*)d_in[5];
    const float* rv1 = (const float*)d_in[6];
    const float* W2  = (const float*)d_in[7];
    const float* b2  = (const float*)d_in[8];
    const float* g2  = (const float*)d_in[9];
    const float* be2 = (const float*)d_in[10];
    const float* rm2 = (const float*)d_in[11];
    const float* rv2 = (const float*)d_in[12];
    const float* W3  = (const float*)d_in[13];
    const float* b3  = (const float*)d_in[14];
    const float* rm3 = (const float*)d_in[15];
    const float* rv3 = (const float*)d_in[16];
    float* out = (float*)d_out;               // reference output dtype: float32

    float* ws = (float*)d_ws;
    size_t off = 0;
    auto alloc = [&](size_t n) { float* p = ws + off; off += n; return p; };

    uint32_t* keybuf = (uint32_t*)alloc(2048);
    float* s1 = alloc(8192); float* o1 = alloc(8192);
    float* s2 = alloc(8192); float* o2 = alloc(8192);
    float* x      = alloc(64 * 2048);
    float* h1     = alloc((size_t)64 * 8192);
    float* h2     = alloc((size_t)64 * 8192);
    float* mstate = alloc(NFLAT);
    float* zstate = alloc(NFLAT);
    size_t fixed = off;                       // ~1.48M floats ≈ 5.9 MB
    float* pbuf = ws + fixed;                 // partials (GEMM phase) / gbuf (scan phase)
    size_t region = (ws_size / 4 > fixed) ? (ws_size / 4 - fixed) : 0;

    const size_t HN = (size_t)64 * 8192;      // 524288
    // k-split degrees, gated by region size (partials buffer = pbuf)
    int KS1 = (region >= 4 * HN) ? 4 : (region >= 2 * HN) ? 2 : 1;
    int KS2 = (region >= 8 * HN) ? 8 : (region >= 4 * HN) ? 4 :
              (region >= 2 * HN) ? 2 : 1;
    int KS3 = (region >= 16 * (size_t)NFLAT) ? 16 : (region >= 8 * (size_t)NFLAT) ? 8 :
              (region >= 4 * (size_t)NFLAT) ? 4 : (region >= 2 * (size_t)NFLAT) ? 2 : 1;

    int Tc = 0;
    const int cands[8] = {128, 64, 32, 16, 8, 4, 2, 1};
    for (int ci = 0; ci < 8; ++ci)
        if ((size_t)cands[ci] * NFLAT <= region) { Tc = cands[ci]; break; }

    keygenF<<<dim3(4), 256, 0, stream>>>(keybuf);
    prep<<<dim3(32), 256, 0, stream>>>(b1, g1, be1, rm1, rv1,
                                       b2, g2, be2, rm2, rv2,
                                       s1, o1, s2, o2);
    fft_x<<<dim3(256), 256, 0, stream>>>(f, x);

    // L1: h1 = x @ W1^T (raw; BN1 folded into L2 staging)
    if (KS1 > 1) {
        gemm_ks<false><<<dim3(64, KS1), 256, 0, stream>>>(
            x, nullptr, nullptr, W1, pbuf, 2048, 2048 / KS1, 8192);
        combineP<<<dim3(2048), 256, 0, stream>>>(pbuf, h1, KS1, (int)HN);
    } else {
        gemm_ks<false><<<dim3(64, 1), 256, 0, stream>>>(
            x, nullptr, nullptr, W1, h1, 2048, 2048, 8192);
    }
    // L2: h2 = relu(bn1(h1)) @ W2^T (raw; BN2 folded into L3 staging)
    if (KS2 > 1) {
        gemm_ks<true><<<dim3(64, KS2), 256, 0, stream>>>(
            h1, s1, o1, W2, pbuf, 8192, 8192 / KS2, 8192);
        combineP<<<dim3(2048), 256, 0, stream>>>(pbuf, h2, KS2, (int)HN);
    } else {
        gemm_ks<true><<<dim3(64, 1), 256, 0, stream>>>(
            h1, s1, o1, W2, h2, 8192, 8192, 8192);
    }
    // L3: mstate = bn3(relu(bn2(h2)) @ W3^T + b3)
    if (KS3 > 1) {
        gemm_ks<true><<<dim3(16, KS3), 256, 0, stream>>>(
            h2, s2, o2, W3, pbuf, 8192, 8192 / KS3, 2048);
        combine3<<<dim3(512), 256, 0, stream>>>(pbuf, b3, rm3, rv3, mstate, KS3);
    } else {
        gemm_ks<true><<<dim3(16, 1), 256, 0, stream>>>(
            h2, s2, o2, W3, h1, 8192, 8192, 2048);   // h1 as temp
        combine3<<<dim3(512), 256, 0, stream>>>(h1, b3, rm3, rv3, mstate, 1);
    }

    if (Tc > 0) {
        float* gbuf = pbuf;                    // reuse region (partials dead now)
        int NC = 1024 / Tc;
        for (int ch = 0; ch < NC; ++ch) {
            precomp_g<<<dim3(512, Tc), 256, 0, stream>>>(keybuf, gbuf, ch * Tc);
            scan_chunk<<<dim3(64), 1024, 0, stream>>>(
                mstate, zstate, gbuf, ch * Tc, Tc, (ch == NC - 1) ? 1 : 0, out);
        }
    } else {
        scan_inline<<<dim3(64), 1024, 0, stream>>>(mstate, keybuf, out);
    }
}

// Round 13
// 992.039 us; speedup vs baseline: 13.9397x; 1.6423x over previous
//
#include <hip/hip_runtime.h>
#include <hip/hip_bf16.h>
#include <stdint.h>

// ---------------------------------------------------------------------------
// Threefry-2x32-20 + JAX partitionable bits (verified passing, rounds 10-12)
// ---------------------------------------------------------------------------
__device__ __forceinline__ uint32_t rotl32(uint32_t v, int s) {
    return (v << s) | (v >> (32 - s));
}

__device__ __forceinline__ void tf2x32(uint32_t k0, uint32_t k1,
                                       uint32_t x0, uint32_t x1,
                                       uint32_t& o0, uint32_t& o1) {
    uint32_t ks2 = k0 ^ k1 ^ 0x1BD11BDAu;
    x0 += k0; x1 += k1;
#define TFR(R0,R1,R2,R3) \
    x0 += x1; x1 = rotl32(x1, R0); x1 ^= x0; \
    x0 += x1; x1 = rotl32(x1, R1); x1 ^= x0; \
    x0 += x1; x1 = rotl32(x1, R2); x1 ^= x0; \
    x0 += x1; x1 = rotl32(x1, R3); x1 ^= x0;
    TFR(13,15,26,6)   x0 += k1;  x1 += ks2 + 1u;
    TFR(17,29,16,24)  x0 += ks2; x1 += k0  + 2u;
    TFR(13,15,26,6)   x0 += k0;  x1 += k1  + 3u;
    TFR(17,29,16,24)  x0 += k1;  x1 += ks2 + 4u;
    TFR(13,15,26,6)   x0 += ks2; x1 += k0  + 5u;
#undef TFR
    o0 = x0; o1 = x1;
}

__device__ __forceinline__ uint32_t pbits32(uint32_t k0, uint32_t k1, uint32_t ctr) {
    uint32_t o0, o1;
    tf2x32(k0, k1, 0u, ctr, o0, o1);
    return o0 ^ o1;
}

#define NROW 64
#define NCOL 2048
#define NFLAT 131072
#define SPLIT 392
#define C2 2.8853900817779268f    // 2/tau * log2(e)

__device__ __forceinline__ float gumbel_from_bits(uint32_t bits) {
    const float TINY = 1.17549435e-38f;
    float f = (float)(bits >> 9) * 1.1920928955078125e-7f;
    float u = fmaxf(TINY, f + TINY);
    return -logf(-logf(u));
}

// ---------------------------------------------------------------------------
// keygen (partitionable foldlike split)
// ---------------------------------------------------------------------------
__global__ __launch_bounds__(256) void keygenF(uint32_t* __restrict__ kb) {
    int n = blockIdx.x * 256 + threadIdx.x;
    uint32_t o0, o1;
    tf2x32(0u, 42u, 0u, (uint32_t)n, o0, o1);
    kb[2 * n] = o0;
    kb[2 * n + 1] = o1;
}

// ---------------------------------------------------------------------------
// FFT real part -> x[64][2048]
// ---------------------------------------------------------------------------
__device__ __constant__ float c_ctab[8] = {
    1.0f, 0.70710678118654752f, 0.0f, -0.70710678118654752f,
   -1.0f, -0.70710678118654752f, 0.0f, 0.70710678118654752f
};

__global__ __launch_bounds__(256) void fft_x(const float* __restrict__ f,
                                             float* __restrict__ x) {
    int gid = blockIdx.x * 256 + threadIdx.x;
    int b = gid >> 10, i = gid & 1023;
    int c = i >> 6, h = (i >> 3) & 7, w = i & 7;
    const float* fb = f + ((b << 4) + c) * 64;
    float s = 0.0f;
#pragma unroll
    for (int hp = 0; hp < 8; ++hp) {
#pragma unroll
        for (int wp = 0; wp < 8; ++wp)
            s += fb[hp * 8 + wp] * c_ctab[(h * hp + w * wp) & 7];
    }
    x[b * NCOL + i] = s;
    x[b * NCOL + 1024 + i] = s;
}

// ---------------------------------------------------------------------------
// prep: fold BN1/BN2 + bias into per-k affine: y = relu(dot*s + o)
// ---------------------------------------------------------------------------
__global__ __launch_bounds__(256) void prep(
    const float* __restrict__ b1, const float* __restrict__ g1,
    const float* __restrict__ be1, const float* __restrict__ rm1, const float* __restrict__ rv1,
    const float* __restrict__ b2, const float* __restrict__ g2,
    const float* __restrict__ be2, const float* __restrict__ rm2, const float* __restrict__ rv2,
    float* __restrict__ s1, float* __restrict__ o1,
    float* __restrict__ s2, float* __restrict__ o2) {
    int i = blockIdx.x * 256 + threadIdx.x;     // [0,8192)
    const float eps = 1e-5f;
    float inv = 1.0f / sqrtf(rv1[i] + eps);
    float s = g1[i] * inv;
    s1[i] = s; o1[i] = (b1[i] - rm1[i]) * s + be1[i];
    inv = 1.0f / sqrtf(rv2[i] + eps);
    s = g2[i] * inv;
    s2[i] = s; o2[i] = (b2[i] - rm2[i]) * s + be2[i];
}

// ---------------------------------------------------------------------------
// fp32 TN GEMM, k-split (structure proven r11/r12)
// ---------------------------------------------------------------------------
template<bool AFF>
__global__ __launch_bounds__(256)
void gemm_ks(const float* __restrict__ A,
             const float* __restrict__ sA, const float* __restrict__ oA,
             const float* __restrict__ B, float* __restrict__ Cpart,
             int K, int Kc, int N) {
    __shared__ float As[32][68];
    __shared__ float Bs[32][132];
    const int t = threadIdx.x;
    const int n0 = blockIdx.x * 128;
    const int k0 = blockIdx.y * Kc;
    const int tm = t >> 4, tn = t & 15;

    float acc[4][8];
#pragma unroll
    for (int i = 0; i < 4; ++i)
#pragma unroll
        for (int j = 0; j < 8; ++j) acc[i][j] = 0.0f;

    for (int kt = k0; kt < k0 + Kc; kt += 32) {
#pragma unroll
        for (int h = 0; h < 2; ++h) {
            int idx = h * 1024 + t * 4;
            int am = idx >> 5, ak = idx & 31;
            size_t go = (size_t)am * K + kt + ak;
            float4 v = *(const float4*)(A + go);
            if (AFF) {
                float4 s = *(const float4*)(sA + kt + ak);
                float4 o = *(const float4*)(oA + kt + ak);
                v.x = fmaxf(v.x * s.x + o.x, 0.0f);
                v.y = fmaxf(v.y * s.y + o.y, 0.0f);
                v.z = fmaxf(v.z * s.z + o.z, 0.0f);
                v.w = fmaxf(v.w * s.w + o.w, 0.0f);
            }
            As[ak + 0][am] = v.x; As[ak + 1][am] = v.y;
            As[ak + 2][am] = v.z; As[ak + 3][am] = v.w;
        }
#pragma unroll
        for (int h = 0; h < 4; ++h) {
            int idx = h * 1024 + t * 4;
            int bn = idx >> 5, bk = idx & 31;
            float4 v = *(const float4*)(B + (size_t)(n0 + bn) * K + kt + bk);
            Bs[bk + 0][bn] = v.x; Bs[bk + 1][bn] = v.y;
            Bs[bk + 2][bn] = v.z; Bs[bk + 3][bn] = v.w;
        }
        __syncthreads();
#pragma unroll 8
        for (int kk = 0; kk < 32; ++kk) {
            float4 av = *(const float4*)&As[kk][tm << 2];
            float4 b0 = *(const float4*)&Bs[kk][tn << 3];
            float4 b1 = *(const float4*)&Bs[kk][(tn << 3) + 4];
            float a4[4] = {av.x, av.y, av.z, av.w};
            float b8[8] = {b0.x, b0.y, b0.z, b0.w, b1.x, b1.y, b1.z, b1.w};
#pragma unroll
            for (int i = 0; i < 4; ++i)
#pragma unroll
                for (int j = 0; j < 8; ++j)
                    acc[i][j] = fmaf(a4[i], b8[j], acc[i][j]);
        }
        __syncthreads();
    }
#pragma unroll
    for (int i = 0; i < 4; ++i) {
        size_t co = (size_t)blockIdx.y * ((size_t)64 * N)
                  + (size_t)((tm << 2) + i) * N + n0 + (tn << 3);
        float4 v0 = {acc[i][0], acc[i][1], acc[i][2], acc[i][3]};
        float4 v1 = {acc[i][4], acc[i][5], acc[i][6], acc[i][7]};
        *(float4*)(Cpart + co) = v0;
        *(float4*)(Cpart + co + 4) = v1;
    }
}

// ---------------------------------------------------------------------------
// combineP: dst = sum of P partials
// ---------------------------------------------------------------------------
__global__ __launch_bounds__(256) void combineP(const float* __restrict__ parts,
                                                float* __restrict__ dst,
                                                int P, int total) {
    int gid = blockIdx.x * 256 + threadIdx.x;
    if (gid >= total) return;
    float s = 0.0f;
    for (int p = 0; p < P; ++p) s += parts[(size_t)p * total + gid];
    dst[gid] = s;
}

// ---------------------------------------------------------------------------
// combine3: mstate = ((sum of P partials) + b3 - rm3) / sqrt(rv3+eps)
// ---------------------------------------------------------------------------
__global__ __launch_bounds__(256) void combine3(const float* __restrict__ parts,
                                                const float* __restrict__ b3,
                                                const float* __restrict__ rm3,
                                                const float* __restrict__ rv3,
                                                float* __restrict__ mstate, int P) {
    int gid = blockIdx.x * 256 + threadIdx.x;   // [0,131072)
    int c = gid & 2047;
    float v = 0.0f;
    for (int p = 0; p < P; ++p) v += parts[(size_t)p * NFLAT + gid];
    mstate[gid] = (v + b3[c] - rm3[c]) / sqrtf(rv3[c] + 1e-5f);
}

// ---------------------------------------------------------------------------
// hash_chunk: grid-stride gumbel precompute (prologue; 256 blocks x 1024)
// gbuf[tt][j] = C2 * gumbel(bits(key[t0+tt], j)), idx = tt*NFLAT + j
// ---------------------------------------------------------------------------
__global__ __launch_bounds__(1024)
void hash_chunk(const uint32_t* __restrict__ kb, float* __restrict__ gbuf,
                int t0, int Tc) {
    size_t total = (size_t)Tc * NFLAT;
    for (size_t idx = (size_t)blockIdx.x * 1024 + threadIdx.x; idx < total;
         idx += (size_t)gridDim.x * 1024) {
        int tt = (int)(idx >> 17);            // / NFLAT
        int j  = (int)(idx & (NFLAT - 1));
        int tg = t0 + tt;
        uint32_t k0 = kb[2 * tg], k1 = kb[2 * tg + 1];
        gbuf[idx] = gumbel_from_bits(pbits32(k0, k1, (uint32_t)j)) * C2;
    }
}

// ---------------------------------------------------------------------------
// scan_fused: blocks 0..63 scan chunk (t0..t0+Tc) from gbufA;
//             blocks 64..255 hash chunk (t0+Tc..t0+2Tc) into gbufB (if !last).
// Scan: prefetched g loads, 1 barrier/iter, rcp normalize.
// ---------------------------------------------------------------------------
__global__ __launch_bounds__(1024)
void scan_fused(float* __restrict__ mstate, float* __restrict__ zstate,
                const float* __restrict__ gbufA, float* __restrict__ gbufB,
                const uint32_t* __restrict__ kb,
                int t0, int Tc, int last, float* __restrict__ out) {
    __shared__ __align__(16) float red[2][16];
    const int tid = threadIdx.x;

    if (blockIdx.x < 64) {
        const int r = blockIdx.x;
        const int c0 = tid, c1 = tid + 1024;
        const int base = r * NCOL;
        float m0 = mstate[base + c0], m1 = mstate[base + c1];
        float z0, z1;
        if (t0 == 0) { z0 = 0.0f; z1 = 0.0f; }
        else         { z0 = zstate[base + c0]; z1 = zstate[base + c1]; }
        const int lane = tid & 63, wid = tid >> 6;

        float g0 = gbufA[base + c0];
        float g1 = gbufA[base + c1];
        for (int tt = 0; tt < Tc; ++tt) {
            float cg0 = g0, cg1 = g1;
            if (tt + 1 < Tc) {                 // prefetch next iteration
                size_t ao = (size_t)(tt + 1) * NFLAT + base;
                g0 = gbufA[ao + c0];
                g1 = gbufA[ao + c1];
            }
            float p0 = exp2f(fmaf(m0, C2, cg0));
            float p1 = exp2f(fmaf(m1, C2, cg1));
            float ps = p0 + p1;
#pragma unroll
            for (int d = 1; d < 64; d <<= 1) ps += __shfl_xor(ps, d, 64);
            if (lane == 0) red[tt & 1][wid] = ps;
            __syncthreads();
            float S;
            {
                const float4* r4 = (const float4*)&red[tt & 1][0];
                float4 v0 = r4[0], v1 = r4[1], v2 = r4[2], v3 = r4[3];
                S = ((v0.x + v0.y) + (v0.z + v0.w)) + ((v1.x + v1.y) + (v1.z + v1.w))
                  + ((v2.x + v2.y) + (v2.z + v2.w)) + ((v3.x + v3.y) + (v3.z + v3.w));
            }
            float rs = __builtin_amdgcn_rcpf(S);
            m0 = p0 * rs; m1 = p1 * rs;
            z0 = fmaxf(z0, m0); z1 = fmaxf(z1, m1);
        }
        mstate[base + c0] = m0; mstate[base + c1] = m1;
        zstate[base + c0] = z0; zstate[base + c1] = z1;
        if (last) {
            if (c0 < SPLIT) out[r * SPLIT + c0] = z0;
            else out[64 * SPLIT + r * (NCOL - SPLIT) + (c0 - SPLIT)] = z0;
            out[64 * SPLIT + r * (NCOL - SPLIT) + (c1 - SPLIT)] = z1;
        }
    } else if (!last) {
        // hash next chunk into gbufB on the other 192 blocks
        int hb = blockIdx.x - 64;              // 0..191
        int tbase = t0 + Tc;
        size_t total = (size_t)Tc * NFLAT;
        for (size_t idx = (size_t)hb * 1024 + tid; idx < total;
             idx += (size_t)192 * 1024) {
            int tt = (int)(idx >> 17);
            int j  = (int)(idx & (NFLAT - 1));
            int tg = tbase + tt;
            uint32_t k0 = kb[2 * tg], k1 = kb[2 * tg + 1];
            gbufB[idx] = gumbel_from_bits(pbits32(k0, k1, (uint32_t)j)) * C2;
        }
    }
}

// ---------------------------------------------------------------------------
// inline-hash fallback (ws too small for gbuf)
// ---------------------------------------------------------------------------
__global__ __launch_bounds__(1024)
void scan_inline(const float* __restrict__ mstate, const uint32_t* __restrict__ kb,
                 float* __restrict__ out) {
    const int r = blockIdx.x;
    const int tid = threadIdx.x;
    const int c0 = tid, c1 = tid + 1024;
    const int base = r * NCOL;
    float m0 = mstate[base + c0], m1 = mstate[base + c1];
    float z0 = 0.0f, z1 = 0.0f;
    __shared__ __align__(16) float red[2][16];
    const int lane = tid & 63, wid = tid >> 6;

    for (int t = 0; t < 1024; ++t) {
        uint32_t k0 = kb[2 * t], k1 = kb[2 * t + 1];
        float g0 = gumbel_from_bits(pbits32(k0, k1, (uint32_t)(base + c0)));
        float g1 = gumbel_from_bits(pbits32(k0, k1, (uint32_t)(base + c1)));
        float p0 = exp2f((m0 + g0) * C2);
        float p1 = exp2f((m1 + g1) * C2);
        float ps = p0 + p1;
#pragma unroll
        for (int d = 1; d < 64; d <<= 1) ps += __shfl_xor(ps, d, 64);
        if (lane == 0) red[t & 1][wid] = ps;
        __syncthreads();
        float S;
        {
            const float4* r4 = (const float4*)&red[t & 1][0];
            float4 v0 = r4[0], v1 = r4[1], v2 = r4[2], v3 = r4[3];
            S = ((v0.x + v0.y) + (v0.z + v0.w)) + ((v1.x + v1.y) + (v1.z + v1.w))
              + ((v2.x + v2.y) + (v2.z + v2.w)) + ((v3.x + v3.y) + (v3.z + v3.w));
        }
        float rs = __builtin_amdgcn_rcpf(S);
        m0 = p0 * rs; m1 = p1 * rs;
        z0 = fmaxf(z0, m0); z1 = fmaxf(z1, m1);
    }
    if (c0 < SPLIT) out[r * SPLIT + c0] = z0;
    else out[64 * SPLIT + r * (NCOL - SPLIT) + (c0 - SPLIT)] = z0;
    out[64 * SPLIT + r * (NCOL - SPLIT) + (c1 - SPLIT)] = z1;
}

// ---------------------------------------------------------------------------
// host
// ---------------------------------------------------------------------------
extern "C" void kernel_launch(void* const* d_in, const int* in_sizes, int n_in,
                              void* d_out, int out_size, void* d_ws, size_t ws_size,
                              hipStream_t stream) {
    const float* f   = (const float*)d_in[0];
    const float* W1  = (const float*)d_in[1];
    const float* b1  = (const float*)d_in[2];
    const float* g1  = (const float*)d_in[3];
    const float* be1 = (const float*)d_in[4];
    const float* rm1 = (const float*)d_in[5];
    const float* rv1 = (const float*)d_in[6];
    const float* W2  = (const float*)d_in[7];
    const float* b2  = (const float*)d_in[8];
    const float* g2  = (const float*)d_in[9];
    const float* be2 = (const float*)d_in[10];
    const float* rm2 = (const float*)d_in[11];
    const float* rv2 = (const float*)d_in[12];
    const float* W3  = (const float*)d_in[13];
    const float* b3  = (const float*)d_in[14];
    const float* rm3 = (const float*)d_in[15];
    const float* rv3 = (const float*)d_in[16];
    float* out = (float*)d_out;               // reference output dtype: float32

    float* ws = (float*)d_ws;
    size_t off = 0;
    auto alloc = [&](size_t n) { float* p = ws + off; off += n; return p; };

    uint32_t* keybuf = (uint32_t*)alloc(2048);
    float* s1 = alloc(8192); float* o1 = alloc(8192);
    float* s2 = alloc(8192); float* o2 = alloc(8192);
    float* x      = alloc(64 * 2048);
    float* h1     = alloc((size_t)64 * 8192);
    float* h2     = alloc((size_t)64 * 8192);
    float* mstate = alloc(NFLAT);
    float* zstate = alloc(NFLAT);
    size_t fixed = off;
    float* pbuf = ws + fixed;                 // partials (GEMM) / gumbel dbuf (scan)
    size_t region = (ws_size / 4 > fixed) ? (ws_size / 4 - fixed) : 0;

    const size_t HN = (size_t)64 * 8192;      // 524288
    int KS1 = (region >= 8 * HN) ? 8 : (region >= 4 * HN) ? 4 :
              (region >= 2 * HN) ? 2 : 1;
    int KS2 = (region >= 16 * HN) ? 16 : (region >= 8 * HN) ? 8 :
              (region >= 4 * HN) ? 4 : (region >= 2 * HN) ? 2 : 1;
    int KS3 = (region >= 16 * (size_t)NFLAT) ? 16 : (region >= 8 * (size_t)NFLAT) ? 8 :
              (region >= 4 * (size_t)NFLAT) ? 4 : (region >= 2 * (size_t)NFLAT) ? 2 : 1;

    int Tc = 0;
    const int cands[5] = {128, 64, 32, 16, 8};
    for (int ci = 0; ci < 5; ++ci)
        if (2 * (size_t)cands[ci] * NFLAT <= region) { Tc = cands[ci]; break; }

    keygenF<<<dim3(4), 256, 0, stream>>>(keybuf);
    prep<<<dim3(32), 256, 0, stream>>>(b1, g1, be1, rm1, rv1,
                                       b2, g2, be2, rm2, rv2,
                                       s1, o1, s2, o2);
    fft_x<<<dim3(256), 256, 0, stream>>>(f, x);

    // L1: h1 = x @ W1^T
    if (KS1 > 1) {
        gemm_ks<false><<<dim3(64, KS1), 256, 0, stream>>>(
            x, nullptr, nullptr, W1, pbuf, 2048, 2048 / KS1, 8192);
        combineP<<<dim3(2048), 256, 0, stream>>>(pbuf, h1, KS1, (int)HN);
    } else {
        gemm_ks<false><<<dim3(64, 1), 256, 0, stream>>>(
            x, nullptr, nullptr, W1, h1, 2048, 2048, 8192);
    }
    // L2: h2 = relu(bn1(h1)) @ W2^T
    if (KS2 > 1) {
        gemm_ks<true><<<dim3(64, KS2), 256, 0, stream>>>(
            h1, s1, o1, W2, pbuf, 8192, 8192 / KS2, 8192);
        combineP<<<dim3(2048), 256, 0, stream>>>(pbuf, h2, KS2, (int)HN);
    } else {
        gemm_ks<true><<<dim3(64, 1), 256, 0, stream>>>(
            h1, s1, o1, W2, h2, 8192, 8192, 8192);
    }
    // L3: mstate = bn3(relu(bn2(h2)) @ W3^T + b3)
    if (KS3 > 1) {
        gemm_ks<true><<<dim3(16, KS3), 256, 0, stream>>>(
            h2, s2, o2, W3, pbuf, 8192, 8192 / KS3, 2048);
        combine3<<<dim3(512), 256, 0, stream>>>(pbuf, b3, rm3, rv3, mstate, KS3);
    } else {
        gemm_ks<true><<<dim3(16, 1), 256, 0, stream>>>(
            h2, s2, o2, W3, h1, 8192, 8192, 2048);
        combine3<<<dim3(512), 256, 0, stream>>>(h1, b3, rm3, rv3, mstate, 1);
    }

    if (Tc > 0) {
        float* gbuf0 = pbuf;
        float* gbuf1 = pbuf + (size_t)Tc * NFLAT;
        int NC = 1024 / Tc;
        // prologue: hash chunk 0 on the full chip
        hash_chunk<<<dim3(256), 1024, 0, stream>>>(keybuf, gbuf0, 0, Tc);
        for (int ch = 0; ch < NC; ++ch) {
            float* ga = (ch & 1) ? gbuf1 : gbuf0;
            float* gb = (ch & 1) ? gbuf0 : gbuf1;
            scan_fused<<<dim3(256), 1024, 0, stream>>>(
                mstate, zstate, ga, gb, keybuf,
                ch * Tc, Tc, (ch == NC - 1) ? 1 : 0, out);
        }
    } else {
        scan_inline<<<dim3(64), 1024, 0, stream>>>(mstate, keybuf, out);
    }
}